// Round 7
// baseline (20.815 us; speedup 1.0000x reference)
//
#include <hip/hip_runtime.h>
#include <hip/hip_bf16.h>

#define NODES 1024
#define DIM   64
#define MINV  1e-15f
#define EPSV  1e-7f
#define WPAD  66

// matches reference: clip to [-1+1e-7, 1-1e-7], 0.5*(log1p(y)-log1p(-y))
__device__ __forceinline__ float artanh_f(float y) {
    y = fminf(fmaxf(y, -1.f + EPSV), 1.f - EPSV);
    return 0.5f * (log1pf(y) - log1pf(-y));
}

__device__ __forceinline__ float waveReduceSum(float v) {
#pragma unroll
    for (int m = 1; m < 64; m <<= 1) v += __shfl_xor(v, m, 64);
    return v;
}

// two independent reductions with interleaved shuffles (halves dependent latency)
__device__ __forceinline__ void waveReduceSum2(float& a, float& b) {
#pragma unroll
    for (int m = 1; m < 64; m <<= 1) {
        const float ta = __shfl_xor(a, m, 64);
        const float tb = __shfl_xor(b, m, 64);
        a += ta; b += tb;
    }
}

// ---------------- Kernel 1: per-node prep (4 rows/block, W staged in LDS) ----------------
__global__ __launch_bounds__(256) void prep_kernel(
    const float* __restrict__ x,
    const float* __restrict__ weight,
    const float* __restrict__ bias,
    const float* __restrict__ att_w,
    float* __restrict__ H, float* __restrict__ X2,
    float* __restrict__ L, float* __restrict__ R)
{
    __shared__ float sx[4][DIM];
    __shared__ float Wl[DIM][WPAD];
    const int tid = threadIdx.x;
    const int wv  = tid >> 6;
    const int t   = tid & 63;
    const int i   = blockIdx.x * 4 + wv;

    // coalesced W fill: 4096 floats by 256 threads x float4
#pragma unroll
    for (int p = 0; p < 4; ++p) {
        const int k = p * 1024 + tid * 4;
        const float4 w4 = *reinterpret_cast<const float4*>(weight + k);
        const int r = k >> 6, c = k & 63;
        Wl[r][c + 0] = w4.x; Wl[r][c + 1] = w4.y;
        Wl[r][c + 2] = w4.z; Wl[r][c + 3] = w4.w;
    }

    const float xd = x[i * DIM + t];
    sx[wv][t] = xd;
    __syncthreads();

    const float xn = fmaxf(sqrtf(waveReduceSum(xd * xd)), MINV);

    float mx = 0.f;
    const float* sxr = sx[wv];
#pragma unroll
    for (int d = 0; d < DIM; d += 2) {
        const float2 w2 = *reinterpret_cast<const float2*>(&Wl[t][d]);
        mx = fmaf(sxr[d + 0], w2.x, mx);
        mx = fmaf(sxr[d + 1], w2.y, mx);
    }

    const float mxn = fmaxf(sqrtf(waveReduceSum(mx * mx)), MINV);
    const float res = tanhf(mxn / xn * artanh_f(xn)) * mx / mxn;   // mobius_matvec (c=1)

    const float bd = bias[t];
    const float bn = fmaxf(sqrtf(waveReduceSum(bd * bd)), MINV);
    const float hb = tanhf(bn) * bd / bn;                          // expmap0(bias)

    const float y2  = waveReduceSum(hb * hb);
    const float x2r = waveReduceSum(res * res);
    const float xy  = waveReduceSum(res * hb);
    const float num = (1.f + 2.f * xy + y2) * res + (1.f - x2r) * hb;
    const float den = fmaxf(1.f + 2.f * xy + x2r * y2, MINV);
    const float h   = num / den;                                   // mobius_add

    const float x2 = waveReduceSum(h * h);
    H[i * DIM + t] = h;

    const float n  = fmaxf(sqrtf(x2), MINV);
    const float ht = artanh_f(n) / n * h;                          // logmap0
    const float Li = waveReduceSum(ht * att_w[t]);
    const float Ri = waveReduceSum(ht * att_w[DIM + t]);

    if (t == 0) { X2[i] = x2; L[i] = Li; R[i] = Ri; }
}

// ---------------- Kernel 2: one wave per row, sparse aggregation + epilogue ----------------
// support_i = -(sum_j f_ij*A_ij) * h_i + B_i * (sum_j f_ij * h_j)
// f_ij = sigmoid(L_i+R_j+b) * coefi * artanh(sn)/sn / den_ij   (adj nonzeros are exactly 1.0)
// EPILOGUE: faithful swapped call expmap(u=h, p=support)
__global__ __launch_bounds__(64) void agg_kernel(
    const float* __restrict__ H, const float* __restrict__ X2,
    const float* __restrict__ L, const float* __restrict__ R,
    const float* __restrict__ adj,
    const float* __restrict__ att_b,
    float* __restrict__ out)
{
    __shared__ float sh[DIM];
    __shared__ float f_arr[NODES];
    __shared__ int   slist[NODES];

    const int i  = blockIdx.x;
    const int ln = threadIdx.x;

    // center row -> register + LDS broadcast copy
    const float hd = H[i * DIM + ln];
    sh[ln] = hd;

    // ---- in-wave compaction: 16 contiguous adj values per lane ----
    unsigned m16 = 0;
    {
        const float4* arow = reinterpret_cast<const float4*>(adj + i * NODES + ln * 16);
#pragma unroll
        for (int q = 0; q < 4; ++q) {
            const float4 a = arow[q];
            m16 |= (a.x != 0.f ? 1u : 0u) << (q * 4 + 0);
            m16 |= (a.y != 0.f ? 1u : 0u) << (q * 4 + 1);
            m16 |= (a.z != 0.f ? 1u : 0u) << (q * 4 + 2);
            m16 |= (a.w != 0.f ? 1u : 0u) << (q * 4 + 3);
        }
    }
    const int cntv = __popc(m16);
    int pfx = cntv;                              // inclusive prefix across wave
#pragma unroll
    for (int d = 1; d < 64; d <<= 1) {
        const int t = __shfl_up(pfx, d, 64);
        if (ln >= d) pfx += t;
    }
    const int cnt = __shfl(pfx, 63, 64);
    int pos = pfx - cntv;
    const int jb = ln * 16;
#pragma unroll
    for (int q = 0; q < 16; ++q)
        if (m16 & (1u << q)) slist[pos++] = jb + q;
    __syncthreads();

    const float x2i   = X2[i];
    const float Li    = L[i];
    const float Bi    = 1.f - x2i;
    const float coefi = fmaxf(Bi, MINV);         // = 2/lambda_i
    const float attb  = att_b[0];

    // ---- phase 2: one pair per lane ----
    float s0 = 0.f;
    for (int k = ln; k < cnt; k += 64) {
        const int j  = slist[k];
        const float y2 = X2[j];
        const float Rj = R[j];

        float dot = 0.f;
        const float* hj = H + j * DIM;
#pragma unroll
        for (int dd = 0; dd < DIM; dd += 4) {
            const float4 h4 = *reinterpret_cast<const float4*>(hj + dd);
            const float4 s4 = *reinterpret_cast<const float4*>(&sh[dd]);  // uniform -> broadcast
            dot = fmaf(h4.x, s4.x, dot);
            dot = fmaf(h4.y, s4.y, dot);
            dot = fmaf(h4.z, s4.z, dot);
            dot = fmaf(h4.w, s4.w, dot);
        }

        const float A   = 1.f - 2.f * dot + y2;
        const float den = fmaxf(1.f - 2.f * dot + x2i * y2, MINV);
        const float q   = fmaxf(A * A * x2i - 2.f * A * Bi * dot + Bi * Bi * y2, 0.f);
        const float sn  = fmaxf(sqrtf(q) / den, MINV);
        const float ratio = artanh_f(sn) / sn;

        const float sig = 1.f / (1.f + expf(-(Li + Rj + attb)));
        const float f   = sig * coefi * ratio / den;     // adj value is exactly 1.0

        f_arr[k] = f;
        s0 += f * A;
    }
    __syncthreads();

    // ---- phase 3: lane-owns-dimension weighted row sum (coalesced re-reads, L2-hit) ----
    float sv = 0.f;
#pragma unroll 4
    for (int k = 0; k < cnt; ++k) {
        const int j   = slist[k];                // uniform LDS read
        const float f = f_arr[k];                // uniform LDS read (broadcast)
        sv = fmaf(f, H[j * DIM + ln], sv);       // 256B coalesced per iteration
    }

    s0 = waveReduceSum(s0);
    const float sup = -s0 * hd + Bi * sv;        // support tangent component (d = ln)

    // ---- FAITHFUL epilogue: out = expmap(u=h, p=support) ----
    const float s2     = waveReduceSum(sup * sup);
    const float coef_s = fmaxf(1.f - s2, MINV);
    const float un     = fmaxf(sqrtf(x2i), MINV);        // ||h||
    const float tt     = tanhf(un / coef_s);
    const float sec    = tt * hd / un;

    float y2s = sec * sec;
    float xy  = sup * sec;
    waveReduceSum2(y2s, xy);
    const float num = (1.f + 2.f * xy + y2s) * sup + (1.f - s2) * sec;
    const float den = fmaxf(1.f + 2.f * xy + s2 * y2s, MINV);
    const float od  = num / den;

    // HypAct: expmap0(relu(logmap0(od)))
    const float on   = fmaxf(sqrtf(waveReduceSum(od * od)), MINV);
    const float tanv = artanh_f(on) / on * od;
    const float tv   = fmaxf(tanv, 0.f);
    const float tn   = fmaxf(sqrtf(waveReduceSum(tv * tv)), MINV);
    const float fin  = tanhf(tn) / tn * tv;

    out[i * DIM + ln] = fin;                     // float32 output
}

extern "C" void kernel_launch(void* const* d_in, const int* in_sizes, int n_in,
                              void* d_out, int out_size, void* d_ws, size_t ws_size,
                              hipStream_t stream) {
    const float* x      = (const float*)d_in[0];
    const float* adj    = (const float*)d_in[1];
    const float* weight = (const float*)d_in[2];
    const float* bias   = (const float*)d_in[3];
    const float* att_w  = (const float*)d_in[4];
    const float* att_b  = (const float*)d_in[5];

    float* ws = (float*)d_ws;
    float* H  = ws;                       // 1024*64
    float* X2 = ws + NODES * DIM;         // 1024
    float* Lb = X2 + NODES;               // 1024
    float* Rb = Lb + NODES;               // 1024

    prep_kernel<<<NODES / 4, 256, 0, stream>>>(x, weight, bias, att_w, H, X2, Lb, Rb);
    agg_kernel<<<NODES, 64, 0, stream>>>(H, X2, Lb, Rb, adj, att_b,
                                         (float*)d_out);
}